// Round 9
// baseline (139.526 us; speedup 1.0000x reference)
//
#include <hip/hip_runtime.h>
#include <math.h>

// Problem constants (from reference setup_inputs): B=16, T=2048, D=512, K=3.
#define B_ 16
#define T_ 2048
#define D_ 512

// ---------------------------------------------------------------------------
// DTYPE EVIDENCE (R0..R8): inputs float32 (R8: hard-coded bf16 reads of
// hidden -> NaN alphas; R4-R7's runtime detector had picked the f32 branch
// and stayed finite). Outputs float32 (R8: 16 bf16 NaN tokens written at
// bf16-element tail offset = f32 element (out_size-16)/2 = MIDDLE of chunk 0
// -> output 0 NaN; bf16-pair-packed tokens read as f32 = ~832.5 artifacts ->
// the exact R4/R5/R6 errors). Layout: natural 4-output f32 concat
// [acoustic B*ML*D | token B | alphas B*T | fires B*T]; ML from out_size.
// ---------------------------------------------------------------------------

// k1: alphas[b,t] = sigmoid(sum_d relu(conv3+res)*lin_w + lin_b).
// One wave per (b,t): lane covers 8 contiguous d (two float4 loads).
__global__ __launch_bounds__(256) void k_alphas(
    const float* __restrict__ hidden,
    const float* __restrict__ conv_w,   // [D,1,3]
    const float* __restrict__ conv_b,   // [D]
    const float* __restrict__ lin_w,    // [1,D]
    const float* __restrict__ lin_b,    // [1]
    float* __restrict__ alpha_ws,       // [B*T] ws
    float* __restrict__ alphas_out)     // [B*T] out chunk 2
{
    const int wid  = blockIdx.x * 4 + (threadIdx.x >> 6);  // b*T + t
    const int lane = threadIdx.x & 63;
    const int t    = wid & (T_ - 1);
    const float* rowc = hidden + (size_t)wid * D_ + lane * 8;

    float hm[8], hc[8], hp[8];
    {
        float4 x = ((const float4*)rowc)[0], y = ((const float4*)rowc)[1];
        hc[0]=x.x; hc[1]=x.y; hc[2]=x.z; hc[3]=x.w;
        hc[4]=y.x; hc[5]=y.y; hc[6]=y.z; hc[7]=y.w;
    }
    if (t > 0) {
        float4 x = ((const float4*)(rowc - D_))[0], y = ((const float4*)(rowc - D_))[1];
        hm[0]=x.x; hm[1]=x.y; hm[2]=x.z; hm[3]=x.w;
        hm[4]=y.x; hm[5]=y.y; hm[6]=y.z; hm[7]=y.w;
    } else {
        for (int i = 0; i < 8; ++i) hm[i] = 0.f;
    }
    if (t < T_ - 1) {
        float4 x = ((const float4*)(rowc + D_))[0], y = ((const float4*)(rowc + D_))[1];
        hp[0]=x.x; hp[1]=x.y; hp[2]=x.z; hp[3]=x.w;
        hp[4]=y.x; hp[5]=y.y; hp[6]=y.z; hp[7]=y.w;
    } else {
        for (int i = 0; i < 8; ++i) hp[i] = 0.f;
    }

    float dot = 0.f;
    #pragma unroll
    for (int i = 0; i < 8; ++i) {
        int d = lane * 8 + i;
        float mem = hm[i] * conv_w[3 * d] + hc[i] * conv_w[3 * d + 1]
                  + hp[i] * conv_w[3 * d + 2] + conv_b[d];
        float o = mem + hc[i];
        o = o > 0.f ? o : 0.f;
        dot += o * lin_w[d];
    }
    #pragma unroll
    for (int off = 32; off > 0; off >>= 1) dot += __shfl_down(dot, off);

    if (lane == 0) {
        float a = 1.f / (1.f + expf(-(dot + lin_b[0])));
        alpha_ws[wid]  = a;
        alphas_out[wid] = a;
    }
}

// k2: fp64 inclusive prefix sum per row; emit S, fire positions, fires, token.
// fire at t iff S_t >= floor(S_{t-1})+1; the fire closes slot floor(S_{t-1}).
__global__ __launch_bounds__(256) void k_scan(
    const float* __restrict__ alpha_ws,
    double* __restrict__ S,             // [B*T] ws
    int*    __restrict__ fire_pos,      // [B*T] ws (slot -> t)
    int*    __restrict__ n_fires,       // [B]   ws
    float*  __restrict__ fires_out,     // [B*T] out chunk 3
    float*  __restrict__ token_out)     // [B]   out chunk 1
{
    const int b = blockIdx.x, tid = threadIdx.x;
    const size_t base = (size_t)b * T_;

    double a[8], tsum = 0.0;
    #pragma unroll
    for (int i = 0; i < 8; ++i) { a[i] = (double)alpha_ws[base + tid * 8 + i]; tsum += a[i]; }

    __shared__ double ssum[256];
    ssum[tid] = tsum;
    __syncthreads();
    for (int off = 1; off < 256; off <<= 1) {
        double v = (tid >= off) ? ssum[tid - off] : 0.0;
        __syncthreads();
        ssum[tid] += v;
        __syncthreads();
    }
    double run = ssum[tid] - tsum;   // exclusive prefix of this thread's chunk

    #pragma unroll
    for (int i = 0; i < 8; ++i) {
        int t = tid * 8 + i;
        double Sp = run, fp = floor(Sp);
        run += a[i];
        S[base + t] = run;
        fires_out[base + t] = (float)(run - fp);       // integ pre-reset
        if (run >= fp + 1.0) fire_pos[base + (long long)fp] = t;  // closes slot fp
    }
    if (tid == 255) {
        n_fires[b]   = (int)floor(run);
        token_out[b] = (float)run;
    }
}

// k3: acoustic[b,s,:] = sum_t w_t * hidden[b,t,:], w_t = overlap of
// [S_{t-1},S_t] with [s,s+1] clamped >=0; t in [fire_pos[s-1], fire_pos[s]].
// One block per (s,b); thread owns 2 f32 cols. s >= nf -> zero-fill.
__global__ __launch_bounds__(256) void k_gather(
    const float*  __restrict__ hidden,
    const double* __restrict__ S,
    const int*    __restrict__ fire_pos,
    const int*    __restrict__ n_fires,
    float* __restrict__ acoustic, int ML)
{
    const int s = blockIdx.x, b = blockIdx.y;
    float2* dst = (float2*)(acoustic + ((size_t)b * ML + s) * D_) + threadIdx.x;

    int nf = n_fires[b];
    if (nf > ML) nf = ML;
    if (s >= nf) { *dst = make_float2(0.f, 0.f); return; }

    const size_t base = (size_t)b * T_;
    const int t_end   = fire_pos[base + s];
    const int t_start = (s == 0) ? 0 : fire_pos[base + s - 1];

    const double vlo = (double)s, vhi = (double)(s + 1);
    float acc0 = 0.f, acc1 = 0.f;
    double Sp = (t_start == 0) ? 0.0 : S[base + t_start - 1];
    const float* hrow = hidden + (base + (size_t)t_start) * D_ + threadIdx.x * 2;
    for (int t = t_start; t <= t_end; ++t, hrow += D_) {
        double St = S[base + t];
        double wd = fmin(St, vhi) - fmax(Sp, vlo);
        float w = wd > 0.0 ? (float)wd : 0.f;
        float2 hv = *(const float2*)hrow;
        acc0 += w * hv.x;
        acc1 += w * hv.y;
        Sp = St;
    }
    *dst = make_float2(acc0, acc1);
}

extern "C" void kernel_launch(void* const* d_in, const int* in_sizes, int n_in,
                              void* d_out, int out_size, void* d_ws, size_t ws_size,
                              hipStream_t stream) {
    (void)in_sizes; (void)n_in; (void)ws_size;
    const float* hidden = (const float*)d_in[0];
    const float* conv_w = (const float*)d_in[1];
    const float* conv_b = (const float*)d_in[2];
    const float* lin_w  = (const float*)d_in[3];
    const float* lin_b  = (const float*)d_in[4];

    const int B = B_, T = T_, D = D_;
    // f32-element layout: [acoustic B*ML*D | token B | alphas B*T | fires B*T]
    int ML = (out_size - (B + 2 * B * T)) / (B * D);
    if (ML < 1) ML = 1;

    float* out        = (float*)d_out;
    float* acoustic   = out;
    float* token_out  = out + (size_t)B * ML * D;
    float* alphas_out = token_out + B;
    float* fires_out  = alphas_out + (size_t)B * T;

    // ws: S f64 first (8B align), then alpha f32, fire_pos i32, n_fires.
    double* S        = (double*)d_ws;                          // 256 KB
    float*  alpha_ws = (float*)(S + (size_t)B * T);            // 128 KB
    int*    fire_pos = (int*)(alpha_ws + (size_t)B * T);       // 128 KB
    int*    n_fires  = fire_pos + (size_t)B * T;               // 64 B

    k_alphas<<<B * T / 4, 256, 0, stream>>>(hidden, conv_w, conv_b, lin_w,
                                            lin_b, alpha_ws, alphas_out);
    k_scan<<<B, 256, 0, stream>>>(alpha_ws, S, fire_pos, n_fires,
                                  fires_out, token_out);
    k_gather<<<dim3(ML, B), 256, 0, stream>>>(hidden, S, fire_pos, n_fires,
                                              acoustic, ML);
}

// Round 10
// 132.709 us; speedup vs baseline: 1.0514x; 1.0514x over previous
//
#include <hip/hip_runtime.h>
#include <math.h>

// Problem constants (from reference setup_inputs): B=16, T=2048, D=512, K=3.
#define B_ 16
#define T_ 2048
#define D_ 512

// ---------------------------------------------------------------------------
// Layout (verified R9): f32 outputs, [acoustic B*ML*D | token B | alphas B*T
// | fires B*T]; f32 inputs. ws: S f64 + fire_pos i32 + n_fires.
// ---------------------------------------------------------------------------

// k1: alphas[b,t] = sigmoid(sum_d relu(conv3+res)*lin_w + lin_b).
// Block = 4 waves; block covers 64 consecutive t of one b; wave owns 16 t,
// lane owns 8 d. Sliding 3-row register window + 1-ahead prefetch: each
// hidden row is read ~1.06x (vs 3x in R9's one-wave-per-t version).
__global__ __launch_bounds__(256) void k_alphas(
    const float* __restrict__ hidden,
    const float* __restrict__ conv_w,   // [D,1,3]
    const float* __restrict__ conv_b,   // [D]
    const float* __restrict__ lin_w,    // [1,D]
    const float* __restrict__ lin_b,    // [1]
    float* __restrict__ alphas_out)     // [B*T] out chunk 2
{
    const int b    = blockIdx.y;
    const int wv   = threadIdx.x >> 6;
    const int lane = threadIdx.x & 63;
    const int t0   = blockIdx.x * 64 + wv * 16;
    const int d0   = lane * 8;

    float w0[8], w1[8], w2[8], cb[8], lw[8];
    #pragma unroll
    for (int i = 0; i < 8; ++i) {
        int d = d0 + i;
        w0[i] = conv_w[3 * d];
        w1[i] = conv_w[3 * d + 1];
        w2[i] = conv_w[3 * d + 2];
        cb[i] = conv_b[d];
        lw[i] = lin_w[d];
    }
    const float lb = lin_b[0];

    const float* rbase = hidden + (size_t)b * T_ * D_ + d0;
    auto loadrow = [&](int t, float* f) {
        const float4* p = (const float4*)(rbase + (size_t)t * D_);
        float4 x = p[0], y = p[1];
        f[0]=x.x; f[1]=x.y; f[2]=x.z; f[3]=x.w;
        f[4]=y.x; f[5]=y.y; f[6]=y.z; f[7]=y.w;
    };

    float hm[8], hc[8], hp[8], nx[8];
    if (t0 > 0) { loadrow(t0 - 1, hm); }
    else        { for (int i = 0; i < 8; ++i) hm[i] = 0.f; }
    loadrow(t0, hc);
    loadrow(t0 + 1, hp);          // t0+1 <= T-15, always in range

    float* aout = alphas_out + (size_t)b * T_;
    #pragma unroll 4
    for (int j = 0; j < 16; ++j) {
        const int t = t0 + j;
        const int tn = t + 2;
        if (tn < T_) { loadrow(tn, nx); }
        else         { for (int i = 0; i < 8; ++i) nx[i] = 0.f; }

        float dot = 0.f;
        #pragma unroll
        for (int i = 0; i < 8; ++i) {
            float mem = fmaf(hm[i], w0[i],
                        fmaf(hc[i], w1[i],
                        fmaf(hp[i], w2[i], cb[i])));
            float o = mem + hc[i];
            o = o > 0.f ? o : 0.f;
            dot += o * lw[i];
        }
        #pragma unroll
        for (int off = 32; off > 0; off >>= 1) dot += __shfl_down(dot, off);
        if (lane == 0) aout[t] = 1.f / (1.f + expf(-(dot + lb)));

        #pragma unroll
        for (int i = 0; i < 8; ++i) { hm[i] = hc[i]; hc[i] = hp[i]; hp[i] = nx[i]; }
    }
}

// k2: fp64 inclusive prefix sum per row (reads alphas from d_out chunk 2);
// emits S, fire positions, fires, token. Verified logic from R9.
__global__ __launch_bounds__(256) void k_scan(
    const float* __restrict__ alphas_in,   // [B*T] (= out chunk 2)
    double* __restrict__ S,                // [B*T] ws
    int*    __restrict__ fire_pos,         // [B*T] ws (slot -> t)
    int*    __restrict__ n_fires,          // [B]   ws
    float*  __restrict__ fires_out,        // [B*T] out chunk 3
    float*  __restrict__ token_out)        // [B]   out chunk 1
{
    const int b = blockIdx.x, tid = threadIdx.x;
    const size_t base = (size_t)b * T_;

    double a[8], tsum = 0.0;
    #pragma unroll
    for (int i = 0; i < 8; ++i) { a[i] = (double)alphas_in[base + tid * 8 + i]; tsum += a[i]; }

    __shared__ double ssum[256];
    ssum[tid] = tsum;
    __syncthreads();
    for (int off = 1; off < 256; off <<= 1) {
        double v = (tid >= off) ? ssum[tid - off] : 0.0;
        __syncthreads();
        ssum[tid] += v;
        __syncthreads();
    }
    double run = ssum[tid] - tsum;   // exclusive prefix of this thread's chunk

    #pragma unroll
    for (int i = 0; i < 8; ++i) {
        int t = tid * 8 + i;
        double Sp = run, fp = floor(Sp);
        run += a[i];
        S[base + t] = run;
        fires_out[base + t] = (float)(run - fp);                  // integ pre-reset
        if (run >= fp + 1.0) fire_pos[base + (long long)fp] = t;  // closes slot fp
    }
    if (tid == 255) {
        n_fires[b]   = (int)floor(run);
        token_out[b] = (float)run;
    }
}

// k3: acoustic[b,s,:] = sum_t w_t * hidden[b,t,:], w_t = overlap of
// [S_{t-1},S_t] with [s,s+1] clamped >=0; t in [fire_pos[s-1], fire_pos[s]].
// One block per (s,b); thread owns 2 f32 cols. s >= nf -> zero-fill.
__global__ __launch_bounds__(256) void k_gather(
    const float*  __restrict__ hidden,
    const double* __restrict__ S,
    const int*    __restrict__ fire_pos,
    const int*    __restrict__ n_fires,
    float* __restrict__ acoustic, int ML)
{
    const int s = blockIdx.x, b = blockIdx.y;
    float2* dst = (float2*)(acoustic + ((size_t)b * ML + s) * D_) + threadIdx.x;

    int nf = n_fires[b];
    if (nf > ML) nf = ML;
    if (s >= nf) { *dst = make_float2(0.f, 0.f); return; }

    const size_t base = (size_t)b * T_;
    const int t_end   = fire_pos[base + s];
    const int t_start = (s == 0) ? 0 : fire_pos[base + s - 1];

    const double vlo = (double)s, vhi = (double)(s + 1);
    float acc0 = 0.f, acc1 = 0.f;
    double Sp = (t_start == 0) ? 0.0 : S[base + t_start - 1];
    const float* hrow = hidden + (base + (size_t)t_start) * D_ + threadIdx.x * 2;
    for (int t = t_start; t <= t_end; ++t, hrow += D_) {
        double St = S[base + t];
        double wd = fmin(St, vhi) - fmax(Sp, vlo);
        float w = wd > 0.0 ? (float)wd : 0.f;
        float2 hv = *(const float2*)hrow;
        acc0 += w * hv.x;
        acc1 += w * hv.y;
        Sp = St;
    }
    *dst = make_float2(acc0, acc1);
}

extern "C" void kernel_launch(void* const* d_in, const int* in_sizes, int n_in,
                              void* d_out, int out_size, void* d_ws, size_t ws_size,
                              hipStream_t stream) {
    (void)in_sizes; (void)n_in; (void)ws_size;
    const float* hidden = (const float*)d_in[0];
    const float* conv_w = (const float*)d_in[1];
    const float* conv_b = (const float*)d_in[2];
    const float* lin_w  = (const float*)d_in[3];
    const float* lin_b  = (const float*)d_in[4];

    const int B = B_, T = T_, D = D_;
    // f32-element layout: [acoustic B*ML*D | token B | alphas B*T | fires B*T]
    int ML = (out_size - (B + 2 * B * T)) / (B * D);
    if (ML < 1) ML = 1;

    float* out        = (float*)d_out;
    float* acoustic   = out;
    float* token_out  = out + (size_t)B * ML * D;
    float* alphas_out = token_out + B;
    float* fires_out  = alphas_out + (size_t)B * T;

    // ws: S f64 first (8B align), then fire_pos i32, n_fires.
    double* S        = (double*)d_ws;                    // 256 KB
    int*    fire_pos = (int*)(S + (size_t)B * T);        // 128 KB
    int*    n_fires  = fire_pos + (size_t)B * T;         // 64 B

    k_alphas<<<dim3(T / 64, B), 256, 0, stream>>>(hidden, conv_w, conv_b,
                                                  lin_w, lin_b, alphas_out);
    k_scan<<<B, 256, 0, stream>>>(alphas_out, S, fire_pos, n_fires,
                                  fires_out, token_out);
    k_gather<<<dim3(ML, B), 256, 0, stream>>>(hidden, S, fire_pos, n_fires,
                                              acoustic, ML);
}